// Round 9
// baseline (159.726 us; speedup 1.0000x reference)
//
#include <hip/hip_runtime.h>
#include <math.h>

#define BB 64
#define II 1024
#define HH 1024

typedef float f4 __attribute__((ext_vector_type(4)));

// ws layout (floats)
#define WS_I     0
#define WS_F     64
#define WS_INVN  128
#define WS_DENOM 192
#define WS_O     256
#define WS_K     (256 + 65536)
#define WS_V     (256 + 2*65536)
#define WS_Q     (256 + 3*65536)

// ---------------- kernel 1: matvec partials (raw x . w_row) ----------------
// grid = 8 k-blocks x 256 row-blocks = 2048 blocks, 256 threads (4 waves).
// Block stages X[0:64][kb*128:+128] into LDS coalesced ([64][129] pad ->
// conflict-free column reads). Wave w owns k-subslice [kb*128+w*32,+32);
// lane = batch; 16 rows/block; weights read exactly once from HBM.
// Partials -> pws[(kb*64+b)*4096 + gr] (in c_out region, consumed by k_fin2
// before k_cup overwrites).
__global__ __launch_bounds__(256) void k_mv2(const float* __restrict__ input,
                                             const float* __restrict__ o_w,
                                             const float* __restrict__ kvq_w,
                                             float* __restrict__ pws) {
    __shared__ float xl[64 * 129];      // 33 KB, padded
    __shared__ float pl[16][4][64];     // 16 KB

    int t = threadIdx.x;
    int w = t >> 6, lane = t & 63;
    int kb = blockIdx.x >> 8;           // 0..7
    int rb = blockIdx.x & 255;          // 0..255
    int k0 = kb * 128 + w * 32;

    // coalesced stage: 64 rows x 32 f4 = 2048 f4, 8 per thread
#pragma unroll
    for (int rep = 0; rep < 8; ++rep) {
        int idx = rep * 256 + t;
        int row = idx >> 5;             // 0..63
        int c4  = idx & 31;             // 0..31
        f4 v = *(const f4*)(input + (size_t)row * II + kb * 128 + c4 * 4);
        float* d = &xl[row * 129 + c4 * 4];
        d[0] = v.x; d[1] = v.y; d[2] = v.z; d[3] = v.w;
    }
    __syncthreads();

    // lane = batch: this wave's 32-float X slice (bank-conflict-free: stride 129)
    const float* xs = &xl[lane * 129 + w * 32];
    float xr[32];
#pragma unroll
    for (int j = 0; j < 32; ++j) xr[j] = xs[j];

#pragma unroll 2
    for (int r = 0; r < 16; ++r) {
        int gr = rb * 16 + r;
        const float* wrow = (gr < HH) ? (o_w + (size_t)gr * II)
                                      : (kvq_w + (size_t)(gr - HH) * II);
        const f4* w4 = (const f4*)(wrow + k0);
        float a0 = 0.f, a1 = 0.f;
#pragma unroll
        for (int q = 0; q < 8; q += 2) {
            f4 u = w4[q], v = w4[q + 1];
            a0 += u.x*xr[4*q+0] + u.y*xr[4*q+1] + u.z*xr[4*q+2] + u.w*xr[4*q+3];
            a1 += v.x*xr[4*q+4] + v.y*xr[4*q+5] + v.z*xr[4*q+6] + v.w*xr[4*q+7];
        }
        pl[r][w][lane] = a0 + a1;
    }
    __syncthreads();

    if (t < 64) {                       // wave 0: reduce 4 wave-partials, write pws
        int b = t;
        float* dst = pws + (((size_t)(kb * 64 + b)) << 12) + rb * 16;
#pragma unroll
        for (int r4 = 0; r4 < 4; ++r4) {
            f4 o;
            o.x = pl[4*r4+0][0][b] + pl[4*r4+0][1][b] + pl[4*r4+0][2][b] + pl[4*r4+0][3][b];
            o.y = pl[4*r4+1][0][b] + pl[4*r4+1][1][b] + pl[4*r4+1][2][b] + pl[4*r4+1][3][b];
            o.z = pl[4*r4+2][0][b] + pl[4*r4+2][1][b] + pl[4*r4+2][2][b] + pl[4*r4+2][3][b];
            o.w = pl[4*r4+3][0][b] + pl[4*r4+3][1][b] + pl[4*r4+3][2][b] + pl[4*r4+3][3][b];
            *(f4*)(dst + 4 * r4) = o;
        }
    }
}

// ---------------- kernel 2: gates + reduce partials + epilogue + denom ----------------
// grid = 64 blocks (one per batch) x 256 threads. Block computes i/f/invn
// itself (12 KB of reads + block reduce), then reduces the 8 k-partials and
// applies the o/k/v/q epilogue + n update + fused denom. Coalesced throughout.
__global__ __launch_bounds__(256) void k_fin2(const float* __restrict__ pws,
                                              const float* __restrict__ input,
                                              const float* __restrict__ if_w,
                                              const float* __restrict__ if_b,
                                              const float* __restrict__ o_b,
                                              const float* __restrict__ kvq_b,
                                              const float* __restrict__ prev_n,
                                              float* __restrict__ ws,
                                              float* __restrict__ n_out) {
    int b = blockIdx.x;
    int t = threadIdx.x;
    int wv = t >> 6, lane = t & 63;

    // gates: d0 = x.if_w0, d1 = x.if_w1, ss = x.x
    f4 xv = *(const f4*)(input + (size_t)b * II + 4 * t);
    f4 g0 = *(const f4*)(if_w + 4 * t);
    f4 g1 = *(const f4*)(if_w + II + 4 * t);
    float d0 = xv.x*g0.x + xv.y*g0.y + xv.z*g0.z + xv.w*g0.w;
    float d1 = xv.x*g1.x + xv.y*g1.y + xv.z*g1.z + xv.w*g1.w;
    float ss = xv.x*xv.x + xv.y*xv.y + xv.z*xv.z + xv.w*xv.w;
#pragma unroll
    for (int off = 32; off > 0; off >>= 1) {
        d0 += __shfl_xor(d0, off);
        d1 += __shfl_xor(d1, off);
        ss += __shfl_xor(ss, off);
    }
    __shared__ float red[3][4];
    if (lane == 0) { red[0][wv] = d0; red[1][wv] = d1; red[2][wv] = ss; }
    __syncthreads();
    float td0 = red[0][0] + red[0][1] + red[0][2] + red[0][3];
    float td1 = red[1][0] + red[1][1] + red[1][2] + red[1][3];
    float tss = red[2][0] + red[2][1] + red[2][2] + red[2][3];
    float ib   = expf(td0 + if_b[0]);
    float fb   = expf(td1 + if_b[1]);
    float invn = 1.0f / sqrtf(tss);
    if (t == 0) {
        ws[WS_I + b]    = ib;
        ws[WS_F + b]    = fb;
        ws[WS_INVN + b] = invn;
    }

    // reduce 8 k-partials per output element
    int hh = 4 * t;
    const float* pb = pws + ((size_t)b << 12);
    f4 d[4];
#pragma unroll
    for (int p = 0; p < 4; ++p) {
        f4 s = {0.f, 0.f, 0.f, 0.f};
#pragma unroll
        for (int kb = 0; kb < 8; ++kb)
            s += *(const f4*)(pb + ((size_t)kb << 18) + p * 1024 + hh);
        d[p] = s;
    }

    // o = sigmoid(d0 + o_b)
    f4 ob = *(const f4*)(o_b + hh);
    f4 o;
    o.x = 1.f / (1.f + expf(-(d[0].x + ob.x)));
    o.y = 1.f / (1.f + expf(-(d[0].y + ob.y)));
    o.z = 1.f / (1.f + expf(-(d[0].z + ob.z)));
    o.w = 1.f / (1.f + expf(-(d[0].w + ob.w)));
    *(f4*)(ws + WS_O + (size_t)b * HH + hh) = o;

    // k = d1*invn/32 + kvq_b[0]; n = f*prev_n + i*k
    f4 kbias = *(const f4*)(kvq_b + hh);
    f4 kv = d[1] * (invn * 0.03125f) + kbias;
    *(f4*)(ws + WS_K + (size_t)b * HH + hh) = kv;
    f4 pn = *(const f4*)(prev_n + (size_t)b * HH + hh);
    f4 nn = pn * fb + kv * ib;
    *(f4*)(n_out + (size_t)b * HH + hh) = nn;

    // v = d2*invn + kvq_b[1]
    f4 vb = *(const f4*)(kvq_b + HH + hh);
    f4 vv = d[2] * invn + vb;
    *(f4*)(ws + WS_V + (size_t)b * HH + hh) = vv;

    // q = d3*invn + kvq_b[2]
    f4 qb = *(const f4*)(kvq_b + 2 * HH + hh);
    f4 qv = d[3] * invn + qb;
    *(f4*)(ws + WS_Q + (size_t)b * HH + hh) = qv;

    // fused denom: block-reduce sum(n*q)
    float s = nn.x*qv.x + nn.y*qv.y + nn.z*qv.z + nn.w*qv.w;
#pragma unroll
    for (int off = 32; off > 0; off >>= 1) s += __shfl_xor(s, off);
    __syncthreads();               // red[] reuse hazard
    if (lane == 0) red[0][wv] = s;
    __syncthreads();
    if (t == 0)
        ws[WS_DENOM + b] = fmaxf(fabsf(red[0][0] + red[0][1] + red[0][2] + red[0][3]), 1.0f);
}

// ---------------- kernel 3: c update + fused readout h ----------------
// Loads batched ahead of compute; PLAIN stores this round (fills sustain
// 6.9 TB/s with plain stores; nt-store was the only policy left untested).
__global__ __launch_bounds__(256) void k_cup(const float* __restrict__ prev_c,
                                             const float* __restrict__ ws,
                                             float* __restrict__ c_out,
                                             float* __restrict__ h_out) {
    int wave = threadIdx.x >> 6, lane = threadIdx.x & 63;
    int g0 = (blockIdx.x * 4 + wave) * 4;    // first of 4 rows, all same batch
    int b = g0 >> 10;
    float fb = ws[WS_F + b], ib = ws[WS_I + b];
    float iv0 = ib * ws[WS_V + g0];
    float iv1 = ib * ws[WS_V + g0 + 1];
    float iv2 = ib * ws[WS_V + g0 + 2];
    float iv3 = ib * ws[WS_V + g0 + 3];
    const f4* pc = (const f4*)(prev_c + ((size_t)g0 << 10));
    f4*       co = (f4*)(c_out + ((size_t)g0 << 10));
    const float4* k4 = (const float4*)(ws + WS_K + (size_t)b * HH);
    const float4* q4 = (const float4*)(ws + WS_Q + (size_t)b * HH);
    float s0 = 0.f, s1 = 0.f, s2 = 0.f, s3 = 0.f;
#pragma unroll
    for (int j = 0; j < 4; ++j) {
        int idx = lane + j * 64;
        float4 kv = k4[idx], qv = q4[idx];
        // batch all 4 row-loads first (4 outstanding 16B loads/lane)
        f4 p0 = pc[idx];
        f4 p1 = pc[idx + 256];
        f4 p2 = pc[idx + 512];
        f4 p3 = pc[idx + 768];
        f4 c;
        c.x = fb*p0.x + iv0*kv.x; c.y = fb*p0.y + iv0*kv.y;
        c.z = fb*p0.z + iv0*kv.z; c.w = fb*p0.w + iv0*kv.w;
        co[idx] = c;
        s0 += c.x*qv.x + c.y*qv.y + c.z*qv.z + c.w*qv.w;

        c.x = fb*p1.x + iv1*kv.x; c.y = fb*p1.y + iv1*kv.y;
        c.z = fb*p1.z + iv1*kv.z; c.w = fb*p1.w + iv1*kv.w;
        co[idx + 256] = c;
        s1 += c.x*qv.x + c.y*qv.y + c.z*qv.z + c.w*qv.w;

        c.x = fb*p2.x + iv2*kv.x; c.y = fb*p2.y + iv2*kv.y;
        c.z = fb*p2.z + iv2*kv.z; c.w = fb*p2.w + iv2*kv.w;
        co[idx + 512] = c;
        s2 += c.x*qv.x + c.y*qv.y + c.z*qv.z + c.w*qv.w;

        c.x = fb*p3.x + iv3*kv.x; c.y = fb*p3.y + iv3*kv.y;
        c.z = fb*p3.z + iv3*kv.z; c.w = fb*p3.w + iv3*kv.w;
        co[idx + 768] = c;
        s3 += c.x*qv.x + c.y*qv.y + c.z*qv.z + c.w*qv.w;
    }
#pragma unroll
    for (int off = 32; off > 0; off >>= 1) {
        s0 += __shfl_xor(s0, off);
        s1 += __shfl_xor(s1, off);
        s2 += __shfl_xor(s2, off);
        s3 += __shfl_xor(s3, off);
    }
    if (lane == 0) {
        float inv_d = 1.0f / ws[WS_DENOM + b];
        h_out[g0]     = ws[WS_O + g0]     * s0 * inv_d;
        h_out[g0 + 1] = ws[WS_O + g0 + 1] * s1 * inv_d;
        h_out[g0 + 2] = ws[WS_O + g0 + 2] * s2 * inv_d;
        h_out[g0 + 3] = ws[WS_O + g0 + 3] * s3 * inv_d;
    }
}

extern "C" void kernel_launch(void* const* d_in, const int* in_sizes, int n_in,
                              void* d_out, int out_size, void* d_ws, size_t ws_size,
                              hipStream_t stream) {
    const float* input  = (const float*)d_in[0];
    const float* prev_c = (const float*)d_in[2];
    const float* prev_n = (const float*)d_in[3];
    const float* if_w   = (const float*)d_in[4];
    const float* o_w    = (const float*)d_in[5];
    const float* kvq_w  = (const float*)d_in[6];
    const float* if_b   = (const float*)d_in[7];
    const float* o_b    = (const float*)d_in[8];
    const float* kvq_b  = (const float*)d_in[9];

    float* out   = (float*)d_out;
    float* h_out = out;                          // [B,H]
    float* c_out = out + 65536;                  // [B,H,H]
    float* n_out = out + 65536 + 67108864;       // [B,H]
    float* ws    = (float*)d_ws;
    float* pws   = c_out;                        // partials scratch inside c region

    k_mv2 <<<2048, 256, 0, stream>>>(input, o_w, kvq_w, pws);
    k_fin2<<<BB, 256, 0, stream>>>(pws, input, if_w, if_b, o_b, kvq_b, prev_n, ws, n_out);
    k_cup <<<4096, 256, 0, stream>>>(prev_c, ws, c_out, h_out);
}

// Round 10
// 120.200 us; speedup vs baseline: 1.3288x; 1.3288x over previous
//
#include <hip/hip_runtime.h>
#include <math.h>

#define BB 64
#define II 1024
#define HH 1024

typedef float f4 __attribute__((ext_vector_type(4)));

// ws layout (floats)
#define WS_I     0
#define WS_F     64
#define WS_INVN  128
#define WS_DENOM 192
#define WS_O     256
#define WS_K     (256 + 65536)
#define WS_V     (256 + 2*65536)
#define WS_Q     (256 + 3*65536)

// ---------------- kernel 1: matvec partials, weights via LDS (coalesced) ----------------
// grid = 4 k-chunks x 256 row-blocks = 1024 blocks, 256 threads (4 waves).
// Block stages W[16 rows][256 k] into LDS with LANE-DISTRIBUTED (coalesced)
// loads -- 1 KB useful bytes per instruction vs 16 B for wave-uniform --
// then compute reads W wave-uniformly from LDS (broadcast, conflict-free).
// X stays in registers: lane = batch, 16 f4 from L2 (256 KB total, L2-hot).
// Wave w owns k-sub [kc*256 + w*64, +64); 16 rows/block; weights read
// exactly once from HBM. Partials -> pws[(kc*64+b)*4096 + gr] (c_out region).
__global__ __launch_bounds__(256) void k_mv3(const float* __restrict__ input,
                                             const float* __restrict__ o_w,
                                             const float* __restrict__ kvq_w,
                                             float* __restrict__ pws) {
    __shared__ float wl[16 * 256];      // 16 KB
    __shared__ float pl[16][4][64];     // 16 KB

    int t = threadIdx.x;
    int w = t >> 6, lane = t & 63;
    int kc = blockIdx.x >> 8;           // 0..3
    int rb = blockIdx.x & 255;          // 0..255
    int gr0 = rb * 16;
    // all 16 rows of a block sit in one weight matrix (16 | 1024)
    const float* wbase = (gr0 < HH) ? (o_w + (size_t)gr0 * II)
                                    : (kvq_w + (size_t)(gr0 - HH) * II);

    // stage W[16][256] coalesced: 1024 f4, 4 per thread
#pragma unroll
    for (int rep = 0; rep < 4; ++rep) {
        int i = rep * 256 + t;
        int row = i >> 6;               // 0..15
        int c4  = i & 63;               // 0..63
        f4 v = *(const f4*)(wbase + (size_t)row * II + kc * 256 + c4 * 4);
        *(f4*)(&wl[row * 256 + c4 * 4]) = v;
    }

    // X slice into registers: lane = batch (uncoalesced but L2-resident)
    const f4* xs = (const f4*)(input + (size_t)lane * II + kc * 256 + w * 64);
    f4 xr[16];
#pragma unroll
    for (int j = 0; j < 16; ++j) xr[j] = xs[j];

    __syncthreads();

    // 16 rows: wave-uniform LDS broadcast reads + 64 FMAs per row per lane
#pragma unroll 2
    for (int r = 0; r < 16; ++r) {
        const f4* wr4 = (const f4*)(&wl[r * 256 + w * 64]);
        float a0 = 0.f, a1 = 0.f;
#pragma unroll
        for (int j = 0; j < 16; j += 2) {
            f4 u = wr4[j], v = wr4[j + 1];
            a0 += u.x*xr[j].x + u.y*xr[j].y + u.z*xr[j].z + u.w*xr[j].w;
            a1 += v.x*xr[j+1].x + v.y*xr[j+1].y + v.z*xr[j+1].z + v.w*xr[j+1].w;
        }
        pl[r][w][lane] = a0 + a1;
    }
    __syncthreads();

    if (t < 64) {                       // wave 0: reduce 4 wave-partials, write pws
        int b = t;
        float* dst = pws + (((size_t)(kc * 64 + b)) << 12) + gr0;
#pragma unroll
        for (int r4 = 0; r4 < 4; ++r4) {
            f4 o;
            o.x = pl[4*r4+0][0][b] + pl[4*r4+0][1][b] + pl[4*r4+0][2][b] + pl[4*r4+0][3][b];
            o.y = pl[4*r4+1][0][b] + pl[4*r4+1][1][b] + pl[4*r4+1][2][b] + pl[4*r4+1][3][b];
            o.z = pl[4*r4+2][0][b] + pl[4*r4+2][1][b] + pl[4*r4+2][2][b] + pl[4*r4+2][3][b];
            o.w = pl[4*r4+3][0][b] + pl[4*r4+3][1][b] + pl[4*r4+3][2][b] + pl[4*r4+3][3][b];
            *(f4*)(dst + 4 * r4) = o;
        }
    }
}

// ---------------- kernel 2: gates + reduce partials + epilogue + denom ----------------
__global__ __launch_bounds__(256) void k_fin2(const float* __restrict__ pws,
                                              const float* __restrict__ input,
                                              const float* __restrict__ if_w,
                                              const float* __restrict__ if_b,
                                              const float* __restrict__ o_b,
                                              const float* __restrict__ kvq_b,
                                              const float* __restrict__ prev_n,
                                              float* __restrict__ ws,
                                              float* __restrict__ n_out) {
    int b = blockIdx.x;
    int t = threadIdx.x;
    int wv = t >> 6, lane = t & 63;

    // gates: d0 = x.if_w0, d1 = x.if_w1, ss = x.x
    f4 xv = *(const f4*)(input + (size_t)b * II + 4 * t);
    f4 g0 = *(const f4*)(if_w + 4 * t);
    f4 g1 = *(const f4*)(if_w + II + 4 * t);
    float d0 = xv.x*g0.x + xv.y*g0.y + xv.z*g0.z + xv.w*g0.w;
    float d1 = xv.x*g1.x + xv.y*g1.y + xv.z*g1.z + xv.w*g1.w;
    float ss = xv.x*xv.x + xv.y*xv.y + xv.z*xv.z + xv.w*xv.w;
#pragma unroll
    for (int off = 32; off > 0; off >>= 1) {
        d0 += __shfl_xor(d0, off);
        d1 += __shfl_xor(d1, off);
        ss += __shfl_xor(ss, off);
    }
    __shared__ float red[3][4];
    if (lane == 0) { red[0][wv] = d0; red[1][wv] = d1; red[2][wv] = ss; }
    __syncthreads();
    float td0 = red[0][0] + red[0][1] + red[0][2] + red[0][3];
    float td1 = red[1][0] + red[1][1] + red[1][2] + red[1][3];
    float tss = red[2][0] + red[2][1] + red[2][2] + red[2][3];
    float ib   = expf(td0 + if_b[0]);
    float fb   = expf(td1 + if_b[1]);
    float invn = 1.0f / sqrtf(tss);
    if (t == 0) {
        ws[WS_I + b]    = ib;
        ws[WS_F + b]    = fb;
        ws[WS_INVN + b] = invn;
    }

    // reduce 4 k-chunk partials per output element
    int hh = 4 * t;
    const float* pb = pws + ((size_t)b << 12);
    f4 d[4];
#pragma unroll
    for (int p = 0; p < 4; ++p) {
        f4 s = {0.f, 0.f, 0.f, 0.f};
#pragma unroll
        for (int kc = 0; kc < 4; ++kc)
            s += *(const f4*)(pb + ((size_t)kc << 18) + p * 1024 + hh);
        d[p] = s;
    }

    // o = sigmoid(d0 + o_b)
    f4 ob = *(const f4*)(o_b + hh);
    f4 o;
    o.x = 1.f / (1.f + expf(-(d[0].x + ob.x)));
    o.y = 1.f / (1.f + expf(-(d[0].y + ob.y)));
    o.z = 1.f / (1.f + expf(-(d[0].z + ob.z)));
    o.w = 1.f / (1.f + expf(-(d[0].w + ob.w)));
    *(f4*)(ws + WS_O + (size_t)b * HH + hh) = o;

    // k = d1*invn/32 + kvq_b[0]; n = f*prev_n + i*k
    f4 kbias = *(const f4*)(kvq_b + hh);
    f4 kv = d[1] * (invn * 0.03125f) + kbias;
    *(f4*)(ws + WS_K + (size_t)b * HH + hh) = kv;
    f4 pn = *(const f4*)(prev_n + (size_t)b * HH + hh);
    f4 nn = pn * fb + kv * ib;
    *(f4*)(n_out + (size_t)b * HH + hh) = nn;

    // v = d2*invn + kvq_b[1]
    f4 vb = *(const f4*)(kvq_b + HH + hh);
    f4 vv = d[2] * invn + vb;
    *(f4*)(ws + WS_V + (size_t)b * HH + hh) = vv;

    // q = d3*invn + kvq_b[2]
    f4 qb = *(const f4*)(kvq_b + 2 * HH + hh);
    f4 qv = d[3] * invn + qb;
    *(f4*)(ws + WS_Q + (size_t)b * HH + hh) = qv;

    // fused denom: block-reduce sum(n*q)
    float s = nn.x*qv.x + nn.y*qv.y + nn.z*qv.z + nn.w*qv.w;
#pragma unroll
    for (int off = 32; off > 0; off >>= 1) s += __shfl_xor(s, off);
    __syncthreads();               // red[] reuse hazard
    if (lane == 0) red[0][wv] = s;
    __syncthreads();
    if (t == 0)
        ws[WS_DENOM + b] = fmaxf(fabsf(red[0][0] + red[0][1] + red[0][2] + red[0][3]), 1.0f);
}

// ---------------- kernel 3: c update + fused readout h (R3-proven: nt load + nt store) ----
__global__ __launch_bounds__(256) void k_cup(const float* __restrict__ prev_c,
                                             const float* __restrict__ ws,
                                             float* __restrict__ c_out,
                                             float* __restrict__ h_out) {
    int wave = threadIdx.x >> 6, lane = threadIdx.x & 63;
    int g0 = (blockIdx.x * 4 + wave) * 4;    // first of 4 rows, all same batch
    int b = g0 >> 10;
    float fb = ws[WS_F + b], ib = ws[WS_I + b];
    float iv0 = ib * ws[WS_V + g0];
    float iv1 = ib * ws[WS_V + g0 + 1];
    float iv2 = ib * ws[WS_V + g0 + 2];
    float iv3 = ib * ws[WS_V + g0 + 3];
    const f4* pc = (const f4*)(prev_c + ((size_t)g0 << 10));
    f4*       co = (f4*)(c_out + ((size_t)g0 << 10));
    const float4* k4 = (const float4*)(ws + WS_K + (size_t)b * HH);
    const float4* q4 = (const float4*)(ws + WS_Q + (size_t)b * HH);
    float s0 = 0.f, s1 = 0.f, s2 = 0.f, s3 = 0.f;
#pragma unroll
    for (int j = 0; j < 4; ++j) {
        int idx = lane + j * 64;
        float4 kv = k4[idx], qv = q4[idx];
        f4 p, c;
        p = __builtin_nontemporal_load(&pc[idx]);
        c.x = fb*p.x + iv0*kv.x; c.y = fb*p.y + iv0*kv.y;
        c.z = fb*p.z + iv0*kv.z; c.w = fb*p.w + iv0*kv.w;
        __builtin_nontemporal_store(c, &co[idx]);
        s0 += c.x*qv.x + c.y*qv.y + c.z*qv.z + c.w*qv.w;

        p = __builtin_nontemporal_load(&pc[idx + 256]);
        c.x = fb*p.x + iv1*kv.x; c.y = fb*p.y + iv1*kv.y;
        c.z = fb*p.z + iv1*kv.z; c.w = fb*p.w + iv1*kv.w;
        __builtin_nontemporal_store(c, &co[idx + 256]);
        s1 += c.x*qv.x + c.y*qv.y + c.z*qv.z + c.w*qv.w;

        p = __builtin_nontemporal_load(&pc[idx + 512]);
        c.x = fb*p.x + iv2*kv.x; c.y = fb*p.y + iv2*kv.y;
        c.z = fb*p.z + iv2*kv.z; c.w = fb*p.w + iv2*kv.w;
        __builtin_nontemporal_store(c, &co[idx + 512]);
        s2 += c.x*qv.x + c.y*qv.y + c.z*qv.z + c.w*qv.w;

        p = __builtin_nontemporal_load(&pc[idx + 768]);
        c.x = fb*p.x + iv3*kv.x; c.y = fb*p.y + iv3*kv.y;
        c.z = fb*p.z + iv3*kv.z; c.w = fb*p.w + iv3*kv.w;
        __builtin_nontemporal_store(c, &co[idx + 768]);
        s3 += c.x*qv.x + c.y*qv.y + c.z*qv.z + c.w*qv.w;
    }
#pragma unroll
    for (int off = 32; off > 0; off >>= 1) {
        s0 += __shfl_xor(s0, off);
        s1 += __shfl_xor(s1, off);
        s2 += __shfl_xor(s2, off);
        s3 += __shfl_xor(s3, off);
    }
    if (lane == 0) {
        float inv_d = 1.0f / ws[WS_DENOM + b];
        h_out[g0]     = ws[WS_O + g0]     * s0 * inv_d;
        h_out[g0 + 1] = ws[WS_O + g0 + 1] * s1 * inv_d;
        h_out[g0 + 2] = ws[WS_O + g0 + 2] * s2 * inv_d;
        h_out[g0 + 3] = ws[WS_O + g0 + 3] * s3 * inv_d;
    }
}

extern "C" void kernel_launch(void* const* d_in, const int* in_sizes, int n_in,
                              void* d_out, int out_size, void* d_ws, size_t ws_size,
                              hipStream_t stream) {
    const float* input  = (const float*)d_in[0];
    const float* prev_c = (const float*)d_in[2];
    const float* prev_n = (const float*)d_in[3];
    const float* if_w   = (const float*)d_in[4];
    const float* o_w    = (const float*)d_in[5];
    const float* kvq_w  = (const float*)d_in[6];
    const float* if_b   = (const float*)d_in[7];
    const float* o_b    = (const float*)d_in[8];
    const float* kvq_b  = (const float*)d_in[9];

    float* out   = (float*)d_out;
    float* h_out = out;                          // [B,H]
    float* c_out = out + 65536;                  // [B,H,H]
    float* n_out = out + 65536 + 67108864;       // [B,H]
    float* ws    = (float*)d_ws;
    float* pws   = c_out;                        // partials scratch inside c region

    k_mv3 <<<1024, 256, 0, stream>>>(input, o_w, kvq_w, pws);
    k_fin2<<<BB, 256, 0, stream>>>(pws, input, if_w, if_b, o_b, kvq_b, prev_n, ws, n_out);
    k_cup <<<4096, 256, 0, stream>>>(prev_c, ws, c_out, h_out);
}